// Round 1
// baseline (379.841 us; speedup 1.0000x reference)
//
#include <hip/hip_runtime.h>
#include <math.h>

typedef __attribute__((ext_vector_type(8))) short short8;
typedef __attribute__((ext_vector_type(4))) float f32x4;

#define NN 2048
#define LL 64
#define DD 128
#define BBATCH 8

__device__ __forceinline__ unsigned short f2bf(float f) {
  unsigned u = __float_as_uint(f);
  u += 0x7fffu + ((u >> 16) & 1u);   // round-to-nearest-even
  return (unsigned short)(u >> 16);
}
__device__ __forceinline__ float sigm(float x) { return 1.0f / (1.0f + expf(-x)); }

// ---------------------------------------------------------------------------
// kA1: T1 = xl_W @ v_W  (128x128);  block 128: cbt = (xl_b + x_pe) @ v_W + v_b
// ---------------------------------------------------------------------------
__global__ __launch_bounds__(128) void kA1(const float* __restrict__ xl_W,
                                           const float* __restrict__ v_W,
                                           const float* __restrict__ xl_b,
                                           const float* __restrict__ x_pe,
                                           const float* __restrict__ v_b,
                                           float* __restrict__ T1,
                                           float* __restrict__ cbt) {
  __shared__ float row[128];
  const int t = threadIdx.x;
  const int k = blockIdx.x;
  if (k < 128) {
    row[t] = xl_W[k * 128 + t];
    __syncthreads();
    float acc = 0.f;
    for (int j = 0; j < 128; ++j) acc += row[j] * v_W[j * 128 + t];
    T1[k * 128 + t] = acc;
  } else {
    row[t] = xl_b[t] + x_pe[t];
    __syncthreads();
    float acc = v_b[t];
    for (int j = 0; j < 128; ++j) acc += row[j] * v_W[j * 128 + t];
    cbt[t] = acc;
  }
}

// ---------------------------------------------------------------------------
// kA2: C = T1 @ out_W, stored transposed+swizzled as bf16 (LDS image);
//      block 128: cb = cbt @ out_W
// LDS image layout: byte = (col*256 + k*2) ^ ((col&7)<<4), col,k in [0,128)
// ---------------------------------------------------------------------------
__global__ __launch_bounds__(128) void kA2(const float* __restrict__ T1,
                                           const float* __restrict__ cbt,
                                           const float* __restrict__ out_W,
                                           unsigned short* __restrict__ ctswz,
                                           float* __restrict__ cb) {
  __shared__ float row[128];
  const int t = threadIdx.x;
  const int k = blockIdx.x;
  if (k < 128) {
    row[t] = T1[k * 128 + t];
    __syncthreads();
    float acc = 0.f;
    for (int j = 0; j < 128; ++j) acc += row[j] * out_W[j * 128 + t];
    // element (row=k, col=t) of C -> Ct[col=t][k]
    int byte = (t * 256 + k * 2) ^ ((t & 7) << 4);
    ctswz[byte >> 1] = f2bf(acc);
  } else {
    row[t] = cbt[t];
    __syncthreads();
    float acc = 0.f;
    for (int j = 0; j < 128; ++j) acc += row[j] * out_W[j * 128 + t];
    cb[t] = acc;
  }
}

// ---------------------------------------------------------------------------
// kC: x_out = x @ C + cb   (1,048,576 rows x 128 @ 128x128), bf16 MFMA
// grid 2048 x 256 threads (4 waves). Each wave: 8 tiles of 16 rows.
// ---------------------------------------------------------------------------
__global__ __launch_bounds__(256) void kC(const float* __restrict__ x,
                                          const unsigned short* __restrict__ ctswz,
                                          const float* __restrict__ cb,
                                          float* __restrict__ out) {
  __shared__ __align__(16) unsigned short lds[128 * 128];
  const int t = threadIdx.x;
  // stage pre-swizzled bf16 C^T image: straight 16B copy
  for (int i = t; i < 2048; i += 256)
    ((f32x4*)lds)[i] = ((const f32x4*)ctswz)[i];
  __syncthreads();

  const int lane = t & 63;
  const int w = t >> 6;
  const int r16 = lane & 15;  // A row within tile / B,D column low bits
  const int g4 = lane >> 4;   // 0..3 lane group

  float cbv[8];
#pragma unroll
  for (int j = 0; j < 8; ++j) cbv[j] = cb[j * 16 + r16];

  int kofs[4];
#pragma unroll
  for (int kt = 0; kt < 4; ++kt)
    kofs[kt] = (kt * 64 + g4 * 16) ^ ((lane & 7) << 4);

  const char* ldsb = (const char*)lds;
  const int gw = blockIdx.x * 4 + w;  // 8192 global waves

  for (int it = 0; it < 8; ++it) {
    const int tile = gw + it * 8192;  // 65536 tiles of 16 rows
    const size_t r0 = (size_t)tile * 16;
    const float* xr = x + (r0 + r16) * 128 + g4 * 8;

    short8 afr[4];
#pragma unroll
    for (int kt = 0; kt < 4; ++kt) {
      f32x4 v0 = *(const f32x4*)(xr + kt * 32);
      f32x4 v1 = *(const f32x4*)(xr + kt * 32 + 4);
      short8 a;
      a[0] = (short)f2bf(v0[0]); a[1] = (short)f2bf(v0[1]);
      a[2] = (short)f2bf(v0[2]); a[3] = (short)f2bf(v0[3]);
      a[4] = (short)f2bf(v1[0]); a[5] = (short)f2bf(v1[1]);
      a[6] = (short)f2bf(v1[2]); a[7] = (short)f2bf(v1[3]);
      afr[kt] = a;
    }

    float* obase = out + (r0 + g4 * 4) * 128 + r16;
#pragma unroll
    for (int j = 0; j < 8; ++j) {
      f32x4 acc = {0.f, 0.f, 0.f, 0.f};
      const int cbyte = (j * 16 + r16) << 8;
#pragma unroll
      for (int kt = 0; kt < 4; ++kt) {
        short8 b = *(const short8*)(ldsb + cbyte + kofs[kt]);
        acc = __builtin_amdgcn_mfma_f32_16x16x32_bf16(afr[kt], b, acc, 0, 0, 0);
      }
      const float c0 = cbv[j];
      obase[j * 16]           = acc[0] + c0;
      obase[j * 16 + 128]     = acc[1] + c0;
      obase[j * 16 + 256]     = acc[2] + c0;
      obase[j * 16 + 384]     = acc[3] + c0;
    }
  }
}

// ---------------------------------------------------------------------------
// kB: per-location selector pipeline. 256 blocks x 256 threads.
// Each block: 8 locations (2 sub-groups of 128 threads x 4 locations).
// ---------------------------------------------------------------------------
#define G_SUB 4
#define GB 8

__global__ __launch_bounds__(256) void kB(
    const float* __restrict__ x, const float* __restrict__ poi,
    const float* __restrict__ sat, const float* __restrict__ loc,
    const float* __restrict__ state,
    const float* __restrict__ poi_W, const float* __restrict__ poi_b, const float* __restrict__ poi_pe,
    const float* __restrict__ sat_W, const float* __restrict__ sat_b, const float* __restrict__ sat_pe,
    const float* __restrict__ xl_W, const float* __restrict__ xl_b, const float* __restrict__ x_pe,
    const float* __restrict__ loc_W, const float* __restrict__ loc_b, const float* __restrict__ loc_pe,
    const float* __restrict__ q_W, const float* __restrict__ q_b,
    const float* __restrict__ v_W, const float* __restrict__ v_b,
    const float* __restrict__ imp_W, const float* __restrict__ imp_b,
    const float* __restrict__ unc_W1, const float* __restrict__ unc_b1,
    const float* __restrict__ unc_W2, const float* __restrict__ unc_b2,
    const float* __restrict__ out_W,
    float* __restrict__ emb1, float* __restrict__ bm) {
  __shared__ float s_poi[GB][64];
  __shared__ float s_sat[GB][128];
  __shared__ float s_loc[GB][32];
  __shared__ float s_xb[GB][128];
  __shared__ float s_q[GB][4][128];
  __shared__ float s_qu[GB][4][128];
  __shared__ float s_va[GB][4][128];
  __shared__ float s_ri[GB][4][2];
  __shared__ float s_ru[GB][4][2];
  __shared__ float s_full[GB][4];

  const int t = threadIdx.x;
  const int sub = t >> 7;
  const int tt = t & 127;
  const int n0 = blockIdx.x * GB;
  const int gbase = sub * G_SUB;

  // ---- stage inputs
  for (int i = t; i < GB * 64; i += 256) s_poi[i >> 6][i & 63] = poi[(n0 + (i >> 6)) * 64 + (i & 63)];
  for (int i = t; i < GB * 128; i += 256) s_sat[i >> 7][i & 127] = sat[(n0 + (i >> 7)) * 128 + (i & 127)];
  for (int i = t; i < GB * 32; i += 256) s_loc[i >> 5][i & 31] = loc[(n0 + (i >> 5)) * 32 + (i & 31)];
  for (int i = t; i < GB * 128; i += 256) {
    int g = i >> 7, k = i & 127;
    float s = 0.f;
#pragma unroll
    for (int b = 0; b < BBATCH; ++b)
      s += x[(size_t)(b * NN + n0 + g) * LL * DD + k];  // l = 0
    s_xb[g][k] = s * 0.125f;
  }
  __syncthreads();

  // ---- phase 2: q[m] projections (thread tt = dim d)
  {
    const int d = tt;
    float acc[G_SUB];
    // m=0 poi
#pragma unroll
    for (int g = 0; g < G_SUB; ++g) acc[g] = 0.f;
    for (int k = 0; k < 64; ++k) {
      float wv = poi_W[k * 128 + d];
#pragma unroll
      for (int g = 0; g < G_SUB; ++g) acc[g] += s_poi[gbase + g][k] * wv;
    }
    { float b0 = poi_b[d] + poi_pe[d];
#pragma unroll
      for (int g = 0; g < G_SUB; ++g) s_q[gbase + g][0][d] = acc[g] + b0; }
    // m=1 sat
#pragma unroll
    for (int g = 0; g < G_SUB; ++g) acc[g] = 0.f;
    for (int k = 0; k < 128; ++k) {
      float wv = sat_W[k * 128 + d];
#pragma unroll
      for (int g = 0; g < G_SUB; ++g) acc[g] += s_sat[gbase + g][k] * wv;
    }
    { float b0 = sat_b[d] + sat_pe[d];
#pragma unroll
      for (int g = 0; g < G_SUB; ++g) s_q[gbase + g][1][d] = acc[g] + b0; }
    // m=2 loc
#pragma unroll
    for (int g = 0; g < G_SUB; ++g) acc[g] = 0.f;
    for (int k = 0; k < 32; ++k) {
      float wv = loc_W[k * 128 + d];
#pragma unroll
      for (int g = 0; g < G_SUB; ++g) acc[g] += s_loc[gbase + g][k] * wv;
    }
    { float b0 = loc_b[d] + loc_pe[d];
#pragma unroll
      for (int g = 0; g < G_SUB; ++g) s_q[gbase + g][2][d] = acc[g] + b0; }
    // m=3 x_cls (mean-over-B folded into s_xb)
#pragma unroll
    for (int g = 0; g < G_SUB; ++g) acc[g] = 0.f;
    for (int k = 0; k < 128; ++k) {
      float wv = xl_W[k * 128 + d];
#pragma unroll
      for (int g = 0; g < G_SUB; ++g) acc[g] += s_xb[gbase + g][k] * wv;
    }
    { float b0 = xl_b[d] + x_pe[d];
#pragma unroll
      for (int g = 0; g < G_SUB; ++g) s_q[gbase + g][3][d] = acc[g] + b0; }
  }
  __syncthreads();

  // ---- phase 3: query / value
  {
    const int d = tt;
    for (int m = 0; m < 4; ++m) {
      float aq[G_SUB], av[G_SUB];
#pragma unroll
      for (int g = 0; g < G_SUB; ++g) { aq[g] = 0.f; av[g] = 0.f; }
      for (int k = 0; k < 128; ++k) {
        float wq = q_W[k * 128 + d];
        float wv = v_W[k * 128 + d];
#pragma unroll
        for (int g = 0; g < G_SUB; ++g) {
          float qv = s_q[gbase + g][m][k];
          aq[g] += qv * wq;
          av[g] += qv * wv;
        }
      }
      float bq = q_b[d], bv = v_b[d];
#pragma unroll
      for (int g = 0; g < G_SUB; ++g) {
        s_qu[gbase + g][m][d] = aq[g] + bq;
        s_va[gbase + g][m][d] = av[g] + bv;
      }
    }
  }
  __syncthreads();

  // ---- phase 4: importance + uncertainty (thread tt = hidden unit k)
  {
    const int k = tt;
    const int wl = (t >> 6) & 1;
    for (int m = 0; m < 4; ++m) {
      float ia[G_SUB], ha[G_SUB];
      const float bi_ = imp_b[m * 128 + k];
      const float bh = unc_b1[m * 128 + k];
#pragma unroll
      for (int g = 0; g < G_SUB; ++g) { ia[g] = bi_; ha[g] = bh; }
      for (int d2 = 0; d2 < 128; ++d2) {
        float wv = imp_W[(m * 256 + d2) * 128 + k];
#pragma unroll
        for (int g = 0; g < G_SUB; ++g) ia[g] += s_qu[gbase + g][m][d2] * wv;
      }
      for (int d2 = 0; d2 < 128; ++d2) {
        float wv = imp_W[(m * 256 + 128 + d2) * 128 + k];
#pragma unroll
        for (int g = 0; g < G_SUB; ++g) ia[g] += s_qu[gbase + g][3][d2] * wv;
      }
      for (int d2 = 0; d2 < 128; ++d2) {
        float wv = unc_W1[(m * 128 + d2) * 128 + k];
#pragma unroll
        for (int g = 0; g < G_SUB; ++g) ha[g] += s_qu[gbase + g][m][d2] * wv;
      }
      const float w2 = unc_W2[m * 128 + k];
#pragma unroll
      for (int g = 0; g < G_SUB; ++g) {
        float a = sigm(ia[g]);
        float hb = fmaxf(ha[g], 0.f) * w2;
#pragma unroll
        for (int off = 32; off > 0; off >>= 1) {
          a += __shfl_down(a, off);
          hb += __shfl_down(hb, off);
        }
        if ((t & 63) == 0) { s_ri[gbase + g][m][wl] = a; s_ru[gbase + g][m][wl] = hb; }
      }
    }
  }
  __syncthreads();
  if (t < GB * 4) {
    int g = t >> 2, m = t & 3;
    float imp = (s_ri[g][m][0] + s_ri[g][m][1]) * (1.f / 128.f);
    float un = sigm(s_ru[g][m][0] + s_ru[g][m][1] + unc_b2[m]);
    float gate = sigm((imp / (1e-6f + un)) * 2.0f);  // /TAU, TAU=0.5
    s_full[g][m] = gate * state[(n0 + g) * 4 + m];
  }
  __syncthreads();
  if (t < GB) {
    int g = t;
    float best = s_full[g][0];
    int bi = 0;
#pragma unroll
    for (int m = 1; m < 4; ++m)
      if (s_full[g][m] > best) { best = s_full[g][m]; bi = m; }
#pragma unroll
    for (int m = 0; m < 4; ++m) {
      float hard = (m == bi || s_full[g][m] > 0.8f) ? 1.f : 0.f;
      bm[(n0 + g) * 4 + m] = hard * state[(n0 + g) * 4 + m];
    }
  }

  // ---- phase 5: emb1 = value @ out_W
  {
    const int d = tt;
    for (int m = 0; m < 4; ++m) {
      float acc[G_SUB];
#pragma unroll
      for (int g = 0; g < G_SUB; ++g) acc[g] = 0.f;
      for (int k = 0; k < 128; ++k) {
        float wv = out_W[k * 128 + d];
#pragma unroll
        for (int g = 0; g < G_SUB; ++g) acc[g] += s_va[gbase + g][m][k] * wv;
      }
#pragma unroll
      for (int g = 0; g < G_SUB; ++g)
        emb1[((size_t)(n0 + gbase + g) * 4 + m) * 128 + d] = acc[g];
    }
  }
}

// ---------------------------------------------------------------------------
extern "C" void kernel_launch(void* const* d_in, const int* in_sizes, int n_in,
                              void* d_out, int out_size, void* d_ws, size_t ws_size,
                              hipStream_t stream) {
  const float* x      = (const float*)d_in[0];
  const float* poi    = (const float*)d_in[1];
  const float* sat    = (const float*)d_in[2];
  const float* loc    = (const float*)d_in[3];
  const float* state  = (const float*)d_in[4];
  const float* poi_W  = (const float*)d_in[5];
  const float* poi_b  = (const float*)d_in[6];
  const float* poi_pe = (const float*)d_in[7];
  const float* sat_W  = (const float*)d_in[8];
  const float* sat_b  = (const float*)d_in[9];
  const float* sat_pe = (const float*)d_in[10];
  const float* xl_W   = (const float*)d_in[11];
  const float* xl_b   = (const float*)d_in[12];
  const float* x_pe   = (const float*)d_in[13];
  const float* loc_W  = (const float*)d_in[14];
  const float* loc_b  = (const float*)d_in[15];
  const float* loc_pe = (const float*)d_in[16];
  const float* q_W    = (const float*)d_in[17];
  const float* q_b    = (const float*)d_in[18];
  const float* v_W    = (const float*)d_in[19];
  const float* v_b    = (const float*)d_in[20];
  const float* imp_W  = (const float*)d_in[21];
  const float* imp_b  = (const float*)d_in[22];
  const float* unc_W1 = (const float*)d_in[23];
  const float* unc_b1 = (const float*)d_in[24];
  const float* unc_W2 = (const float*)d_in[25];
  const float* unc_b2 = (const float*)d_in[26];
  const float* out_W  = (const float*)d_in[27];

  float* out  = (float*)d_out;
  float* emb1 = out;                                    // [2048,4,128]
  float* xout = out + (size_t)2048 * 4 * 128;           // [8,2048,64,128]
  float* bm   = xout + (size_t)8 * 2048 * 64 * 128;     // [2048,4,1]

  float* T1  = (float*)d_ws;             // 128*128 f32
  float* cbt = T1 + 128 * 128;           // 128 f32
  float* cb  = cbt + 128;                // 128 f32
  unsigned short* ctswz = (unsigned short*)(cb + 128);  // 128*128 bf16, swizzled

  kA1<<<dim3(129), dim3(128), 0, stream>>>(xl_W, v_W, xl_b, x_pe, v_b, T1, cbt);
  kA2<<<dim3(129), dim3(128), 0, stream>>>(T1, cbt, out_W, ctswz, cb);
  kC<<<dim3(2048), dim3(256), 0, stream>>>(x, ctswz, cb, xout);
  kB<<<dim3(256), dim3(256), 0, stream>>>(x, poi, sat, loc, state,
      poi_W, poi_b, poi_pe, sat_W, sat_b, sat_pe, xl_W, xl_b, x_pe,
      loc_W, loc_b, loc_pe, q_W, q_b, v_W, v_b, imp_W, imp_b,
      unc_W1, unc_b1, unc_W2, unc_b2, out_W, emb1, bm);
}

// Round 2
// 265.013 us; speedup vs baseline: 1.4333x; 1.4333x over previous
//
#include <hip/hip_runtime.h>
#include <math.h>

typedef __attribute__((ext_vector_type(8))) short short8;
typedef __attribute__((ext_vector_type(4))) float f32x4;

#define NN 2048
#define LL 64
#define DD 128
#define BBATCH 8
#define LOCB 8

// packed-weight offsets (bf16 element units)
#define PK_Q    0
#define PK_V    16384
#define PK_OUT  32768
#define PK_POI  49152
#define PK_SAT  57344
#define PK_LOC  73728
#define PK_XL   77824
#define PK_IMP  94208
#define PK_UNC  225280
#define PK_TOTAL 290816

__device__ __forceinline__ unsigned short f2bf(float f) {
  unsigned u = __float_as_uint(f);
  u += 0x7fffu + ((u >> 16) & 1u);   // round-to-nearest-even
  return (unsigned short)(u >> 16);
}
__device__ __forceinline__ float sigm(float x) { return 1.0f / (1.0f + expf(-x)); }

// ---------------------------------------------------------------------------
// kA1: T1 = xl_W @ v_W  (128x128);  block 128: cbt = (xl_b + x_pe) @ v_W + v_b
// ---------------------------------------------------------------------------
__global__ __launch_bounds__(128) void kA1(const float* __restrict__ xl_W,
                                           const float* __restrict__ v_W,
                                           const float* __restrict__ xl_b,
                                           const float* __restrict__ x_pe,
                                           const float* __restrict__ v_b,
                                           float* __restrict__ T1,
                                           float* __restrict__ cbt) {
  __shared__ float row[128];
  const int t = threadIdx.x;
  const int k = blockIdx.x;
  if (k < 128) {
    row[t] = xl_W[k * 128 + t];
    __syncthreads();
    float acc = 0.f;
    for (int j = 0; j < 128; ++j) acc += row[j] * v_W[j * 128 + t];
    T1[k * 128 + t] = acc;
  } else {
    row[t] = xl_b[t] + x_pe[t];
    __syncthreads();
    float acc = v_b[t];
    for (int j = 0; j < 128; ++j) acc += row[j] * v_W[j * 128 + t];
    cbt[t] = acc;
  }
}

// ---------------------------------------------------------------------------
// kA2: C = T1 @ out_W, stored transposed+swizzled bf16; block 128: cb
// ---------------------------------------------------------------------------
__global__ __launch_bounds__(128) void kA2(const float* __restrict__ T1,
                                           const float* __restrict__ cbt,
                                           const float* __restrict__ out_W,
                                           unsigned short* __restrict__ ctswz,
                                           float* __restrict__ cb) {
  __shared__ float row[128];
  const int t = threadIdx.x;
  const int k = blockIdx.x;
  if (k < 128) {
    row[t] = T1[k * 128 + t];
    __syncthreads();
    float acc = 0.f;
    for (int j = 0; j < 128; ++j) acc += row[j] * out_W[j * 128 + t];
    int byte = (t * 256 + k * 2) ^ ((t & 7) << 4);
    ctswz[byte >> 1] = f2bf(acc);
  } else {
    row[t] = cbt[t];
    __syncthreads();
    float acc = 0.f;
    for (int j = 0; j < 128; ++j) acc += row[j] * out_W[j * 128 + t];
    cb[t] = acc;
  }
}

// ---------------------------------------------------------------------------
// kW: pack all selector weights into bf16 fragment-major layout.
// dst[idx]; idx -> (segment, local); local = ((j*KT + kt)*64 + lane)*8 + e
// value = W[(kt*32 + (lane>>4)*8 + e)*128 + (j*16 + (lane&15))]
// ---------------------------------------------------------------------------
__global__ __launch_bounds__(256) void kW(const float* __restrict__ q_W,
                                          const float* __restrict__ v_W,
                                          const float* __restrict__ out_W,
                                          const float* __restrict__ poi_W,
                                          const float* __restrict__ sat_W,
                                          const float* __restrict__ loc_W,
                                          const float* __restrict__ xl_W,
                                          const float* __restrict__ imp_W,
                                          const float* __restrict__ unc_W1,
                                          unsigned short* __restrict__ dst) {
  int idx = blockIdx.x * 256 + threadIdx.x;
  if (idx >= PK_TOTAL) return;
  const float* src;
  int K, local;
  if (idx < PK_V)        { src = q_W;   K = 128; local = idx - PK_Q; }
  else if (idx < PK_OUT) { src = v_W;   K = 128; local = idx - PK_V; }
  else if (idx < PK_POI) { src = out_W; K = 128; local = idx - PK_OUT; }
  else if (idx < PK_SAT) { src = poi_W; K = 64;  local = idx - PK_POI; }
  else if (idx < PK_LOC) { src = sat_W; K = 128; local = idx - PK_SAT; }
  else if (idx < PK_XL)  { src = loc_W; K = 32;  local = idx - PK_LOC; }
  else if (idx < PK_IMP) { src = xl_W;  K = 128; local = idx - PK_XL; }
  else if (idx < PK_UNC) { int l = idx - PK_IMP; int m = l >> 15; src = imp_W + m * 256 * 128; K = 256; local = l & 32767; }
  else                   { int l = idx - PK_UNC; int m = l >> 14; src = unc_W1 + m * 128 * 128; K = 128; local = l & 16383; }
  int e = local & 7, lane = (local >> 3) & 63, rest = local >> 9;
  int KT = K >> 5;
  int kt = rest % KT, j = rest / KT;
  int k = kt * 32 + (lane >> 4) * 8 + e;
  int col = j * 16 + (lane & 15);
  dst[idx] = f2bf(src[k * 128 + col]);
}

// ---------------------------------------------------------------------------
// kC: x_out = x @ C + cb, bf16 MFMA, register-prefetched across tiles.
// ---------------------------------------------------------------------------
__global__ __launch_bounds__(256) void kC(const float* __restrict__ x,
                                          const unsigned short* __restrict__ ctswz,
                                          const float* __restrict__ cb,
                                          float* __restrict__ out) {
  __shared__ __align__(16) unsigned short lds[128 * 128];
  const int t = threadIdx.x;
  for (int i = t; i < 2048; i += 256)
    ((f32x4*)lds)[i] = ((const f32x4*)ctswz)[i];
  __syncthreads();

  const int lane = t & 63;
  const int w = t >> 6;
  const int r16 = lane & 15;
  const int g4 = lane >> 4;

  float cbv[8];
#pragma unroll
  for (int j = 0; j < 8; ++j) cbv[j] = cb[j * 16 + r16];

  int kofs[4];
#pragma unroll
  for (int kt = 0; kt < 4; ++kt)
    kofs[kt] = (kt * 64 + g4 * 16) ^ ((lane & 7) << 4);

  const char* ldsb = (const char*)lds;
  const int gw = blockIdx.x * 4 + w;

  f32x4 raw0[4], raw1[4];
  {
    const float* xr = x + ((size_t)gw * 16 + r16) * 128 + g4 * 8;
#pragma unroll
    for (int kt = 0; kt < 4; ++kt) {
      raw0[kt] = *(const f32x4*)(xr + kt * 32);
      raw1[kt] = *(const f32x4*)(xr + kt * 32 + 4);
    }
  }

  for (int it = 0; it < 8; ++it) {
    const size_t r0 = ((size_t)gw + (size_t)it * 8192) * 16;

    short8 afr[4];
#pragma unroll
    for (int kt = 0; kt < 4; ++kt) {
      short8 a;
      a[0] = (short)f2bf(raw0[kt][0]); a[1] = (short)f2bf(raw0[kt][1]);
      a[2] = (short)f2bf(raw0[kt][2]); a[3] = (short)f2bf(raw0[kt][3]);
      a[4] = (short)f2bf(raw1[kt][0]); a[5] = (short)f2bf(raw1[kt][1]);
      a[6] = (short)f2bf(raw1[kt][2]); a[7] = (short)f2bf(raw1[kt][3]);
      afr[kt] = a;
    }

    if (it < 7) {  // prefetch next tile while this tile computes
      const float* xn = x + (((size_t)gw + (size_t)(it + 1) * 8192) * 16 + r16) * 128 + g4 * 8;
#pragma unroll
      for (int kt = 0; kt < 4; ++kt) {
        raw0[kt] = *(const f32x4*)(xn + kt * 32);
        raw1[kt] = *(const f32x4*)(xn + kt * 32 + 4);
      }
    }

    float* obase = out + (r0 + g4 * 4) * 128 + r16;
#pragma unroll
    for (int j = 0; j < 8; ++j) {
      f32x4 acc = {0.f, 0.f, 0.f, 0.f};
      const int cbyte = (j * 16 + r16) << 8;
#pragma unroll
      for (int kt = 0; kt < 4; ++kt) {
        short8 b = *(const short8*)(ldsb + cbyte + kofs[kt]);
        acc = __builtin_amdgcn_mfma_f32_16x16x32_bf16(afr[kt], b, acc, 0, 0, 0);
      }
      const float c0 = cbv[j];
      obase[j * 16]       = acc[0] + c0;
      obase[j * 16 + 128] = acc[1] + c0;
      obase[j * 16 + 256] = acc[2] + c0;
      obase[j * 16 + 384] = acc[3] + c0;
    }
  }
}

// ---------------------------------------------------------------------------
// kB: MFMA selector. 256 blocks x 256 threads; block = 8 locations; wave = m.
// LDS A-tiles (16x128 bf16), short-index swizzle: (row*128+col)^((row&7)<<3)
// ---------------------------------------------------------------------------
__device__ __forceinline__ short8 ldb(const unsigned short* pkW, int j, int kt, int KT) {
  return *(const short8*)(pkW + (size_t)(((j * KT + kt) * 64) + (threadIdx.x & 63)) * 8);
}

__global__ __launch_bounds__(256) void kB(
    const float* __restrict__ x, const float* __restrict__ poi,
    const float* __restrict__ sat, const float* __restrict__ loc,
    const float* __restrict__ state,
    const float* __restrict__ poi_b, const float* __restrict__ poi_pe,
    const float* __restrict__ sat_b, const float* __restrict__ sat_pe,
    const float* __restrict__ loc_b, const float* __restrict__ loc_pe,
    const float* __restrict__ xl_b, const float* __restrict__ x_pe,
    const float* __restrict__ q_b, const float* __restrict__ v_b,
    const float* __restrict__ imp_b, const float* __restrict__ unc_b1,
    const float* __restrict__ unc_W2, const float* __restrict__ unc_b2,
    const unsigned short* __restrict__ pk,
    float* __restrict__ emb1, float* __restrict__ bm) {
  // sA: [0..3]=q tiles, [4..7]=qu tiles, [8..11]=va tiles, [12]=xb tile
  __shared__ __align__(16) unsigned short sA[13 * 2048];
  __shared__ float s_full[LOCB][4];

  const int t = threadIdx.x;
  const int m = t >> 6;
  const int lane = t & 63;
  const int r16 = lane & 15, g4 = lane >> 4;
  const int n0 = blockIdx.x * LOCB;

  // zero LDS (rows 8..15 of every tile must be finite)
  for (int i = t; i < 13 * 1024; i += 256) ((unsigned*)sA)[i] = 0u;
  __syncthreads();

  // P0: xb = mean_b x[b, n0+l, 0, :]  -> xb tile (bf16, swizzled)
  for (int s = t; s < LOCB * 128; s += 256) {
    int l = s >> 7, d = s & 127;
    const float* xp = x + ((size_t)(n0 + l) * LL) * DD + d;
    float acc = 0.f;
#pragma unroll
    for (int b = 0; b < BBATCH; ++b) acc += xp[(size_t)b * NN * LL * DD];
    sA[12 * 2048 + ((l * 128 + d) ^ ((l & 7) << 3))] = f2bf(acc * 0.125f);
  }
  __syncthreads();

  // ---- P1: q[m] = input_m @ W_m + b_m + pe_m   -> q tile (wave-local)
  {
    const int KTm = (m == 0) ? 2 : ((m == 2) ? 1 : 4);
    const unsigned short* pkW =
        pk + (m == 0 ? PK_POI : m == 1 ? PK_SAT : m == 2 ? PK_LOC : PK_XL);
    const float* bb = (m == 0) ? poi_b : (m == 1) ? sat_b : (m == 2) ? loc_b : xl_b;
    const float* pe = (m == 0) ? poi_pe : (m == 1) ? sat_pe : (m == 2) ? loc_pe : x_pe;

    short8 af[4];
#pragma unroll
    for (int kt = 0; kt < 4; ++kt) af[kt] = (short8)0;
    if (m < 3) {
      const float* src = (m == 0) ? poi : (m == 1) ? sat : loc;
      const int KD = (m == 0) ? 64 : (m == 1) ? 128 : 32;
      const int locA = (r16 < LOCB) ? r16 : (LOCB - 1);
      const float* ar = src + (size_t)(n0 + locA) * KD + g4 * 8;
#pragma unroll
      for (int kt = 0; kt < 4; ++kt) {
        if (kt < KTm) {
          f32x4 v0 = *(const f32x4*)(ar + kt * 32);
          f32x4 v1 = *(const f32x4*)(ar + kt * 32 + 4);
          short8 a;
          a[0] = (short)f2bf(v0[0]); a[1] = (short)f2bf(v0[1]);
          a[2] = (short)f2bf(v0[2]); a[3] = (short)f2bf(v0[3]);
          a[4] = (short)f2bf(v1[0]); a[5] = (short)f2bf(v1[1]);
          a[6] = (short)f2bf(v1[2]); a[7] = (short)f2bf(v1[3]);
          af[kt] = a;
        }
      }
    } else {
      const unsigned short* tile = sA + 12 * 2048;
#pragma unroll
      for (int kt = 0; kt < 4; ++kt)
        af[kt] = *(const short8*)(tile + ((r16 * 128 + kt * 32 + g4 * 8) ^ ((r16 & 7) << 3)));
    }

    unsigned short* tq = sA + m * 2048;
#pragma unroll
    for (int j = 0; j < 8; ++j) {
      f32x4 acc = {0.f, 0.f, 0.f, 0.f};
#pragma unroll
      for (int kt = 0; kt < 4; ++kt)
        if (kt < KTm) acc = __builtin_amdgcn_mfma_f32_16x16x32_bf16(af[kt], ldb(pkW, j, kt, KTm), acc, 0, 0, 0);
      const int bcol = j * 16 + r16;
      const float badd = bb[bcol] + pe[bcol];
      if (g4 < 2) {
#pragma unroll
        for (int r = 0; r < 4; ++r) {
          int row = g4 * 4 + r;
          tq[(row * 128 + bcol) ^ ((row & 7) << 3)] = f2bf(acc[r] + badd);
        }
      }
    }
  }

  // ---- P2: qu = q@q_W + q_b ; va = q@v_W + v_b (wave-local read of own q)
  {
    const unsigned short* tile = sA + m * 2048;
    short8 aq[4];
#pragma unroll
    for (int kt = 0; kt < 4; ++kt)
      aq[kt] = *(const short8*)(tile + ((r16 * 128 + kt * 32 + g4 * 8) ^ ((r16 & 7) << 3)));
    unsigned short* tu = sA + (4 + m) * 2048;
    unsigned short* tv = sA + (8 + m) * 2048;
#pragma unroll
    for (int j = 0; j < 8; ++j) {
      f32x4 aQ = {0.f, 0.f, 0.f, 0.f}, aV = {0.f, 0.f, 0.f, 0.f};
#pragma unroll
      for (int kt = 0; kt < 4; ++kt) {
        aQ = __builtin_amdgcn_mfma_f32_16x16x32_bf16(aq[kt], ldb(pk + PK_Q, j, kt, 4), aQ, 0, 0, 0);
        aV = __builtin_amdgcn_mfma_f32_16x16x32_bf16(aq[kt], ldb(pk + PK_V, j, kt, 4), aV, 0, 0, 0);
      }
      const int bcol = j * 16 + r16;
      const float bq = q_b[bcol], bv = v_b[bcol];
      if (g4 < 2) {
#pragma unroll
        for (int r = 0; r < 4; ++r) {
          int row = g4 * 4 + r;
          tu[(row * 128 + bcol) ^ ((row & 7) << 3)] = f2bf(aQ[r] + bq);
          tv[(row * 128 + bcol) ^ ((row & 7) << 3)] = f2bf(aV[r] + bv);
        }
      }
    }
  }
  __syncthreads();  // qu[3] needed by all waves

  // ---- P3: imp (sigmoid-mean) + unc -> gate -> s_full
  {
    const unsigned short* tu = sA + (4 + m) * 2048;
    const unsigned short* t3 = sA + (4 + 3) * 2048;
    short8 au[4], a3[4];
#pragma unroll
    for (int kt = 0; kt < 4; ++kt) {
      au[kt] = *(const short8*)(tu + ((r16 * 128 + kt * 32 + g4 * 8) ^ ((r16 & 7) << 3)));
      a3[kt] = *(const short8*)(t3 + ((r16 * 128 + kt * 32 + g4 * 8) ^ ((r16 & 7) << 3)));
    }
    const unsigned short* pkimp = pk + PK_IMP + m * 32768;
    const unsigned short* pkun = pk + PK_UNC + m * 16384;
    float impsum[4] = {0.f, 0.f, 0.f, 0.f};
    float uncsum[4] = {0.f, 0.f, 0.f, 0.f};
#pragma unroll
    for (int j = 0; j < 8; ++j) {
      f32x4 ai = {0.f, 0.f, 0.f, 0.f}, ah = {0.f, 0.f, 0.f, 0.f};
#pragma unroll
      for (int kt = 0; kt < 4; ++kt) {
        ai = __builtin_amdgcn_mfma_f32_16x16x32_bf16(au[kt], ldb(pkimp, j, kt, 8), ai, 0, 0, 0);
        ai = __builtin_amdgcn_mfma_f32_16x16x32_bf16(a3[kt], ldb(pkimp, j, kt + 4, 8), ai, 0, 0, 0);
        ah = __builtin_amdgcn_mfma_f32_16x16x32_bf16(au[kt], ldb(pkun, j, kt, 4), ah, 0, 0, 0);
      }
      const int bcol = j * 16 + r16;
      const float bi = imp_b[m * 128 + bcol];
      const float bh = unc_b1[m * 128 + bcol];
      const float w2 = unc_W2[m * 128 + bcol];
#pragma unroll
      for (int r = 0; r < 4; ++r) {
        impsum[r] += sigm(ai[r] + bi);
        uncsum[r] += fmaxf(ah[r] + bh, 0.f) * w2;
      }
    }
#pragma unroll
    for (int off = 1; off <= 8; off <<= 1) {
#pragma unroll
      for (int r = 0; r < 4; ++r) {
        impsum[r] += __shfl_xor(impsum[r], off);
        uncsum[r] += __shfl_xor(uncsum[r], off);
      }
    }
    if (g4 < 2 && r16 == 0) {
      const float b2 = unc_b2[m];
#pragma unroll
      for (int r = 0; r < 4; ++r) {
        int l = g4 * 4 + r;
        float imp = impsum[r] * (1.f / 128.f);
        float un = sigm(uncsum[r] + b2);
        float gate = sigm(2.f * imp / (1e-6f + un));
        s_full[l][m] = gate * state[(n0 + l) * 4 + m];
      }
    }
  }
  __syncthreads();

  // ---- P4: BinaryMaskSTE forward (threads 0..7)
  if (t < LOCB) {
    float f[4];
#pragma unroll
    for (int mm = 0; mm < 4; ++mm) f[mm] = s_full[t][mm];
    int bi = 0;
    float best = f[0];
#pragma unroll
    for (int mm = 1; mm < 4; ++mm)
      if (f[mm] > best) { best = f[mm]; bi = mm; }
#pragma unroll
    for (int mm = 0; mm < 4; ++mm) {
      float hard = (mm == bi || f[mm] > 0.8f) ? 1.f : 0.f;
      bm[(n0 + t) * 4 + mm] = hard * state[(n0 + t) * 4 + mm];
    }
  }

  // ---- P5: emb1 = va @ out_W (wave-local va tile)
  {
    const unsigned short* tv = sA + (8 + m) * 2048;
    short8 av[4];
#pragma unroll
    for (int kt = 0; kt < 4; ++kt)
      av[kt] = *(const short8*)(tv + ((r16 * 128 + kt * 32 + g4 * 8) ^ ((r16 & 7) << 3)));
#pragma unroll
    for (int j = 0; j < 8; ++j) {
      f32x4 acc = {0.f, 0.f, 0.f, 0.f};
#pragma unroll
      for (int kt = 0; kt < 4; ++kt)
        acc = __builtin_amdgcn_mfma_f32_16x16x32_bf16(av[kt], ldb(pk + PK_OUT, j, kt, 4), acc, 0, 0, 0);
      const int bcol = j * 16 + r16;
      if (g4 < 2) {
#pragma unroll
        for (int r = 0; r < 4; ++r)
          emb1[((size_t)(n0 + g4 * 4 + r) * 4 + m) * 128 + bcol] = acc[r];
      }
    }
  }
}

// ---------------------------------------------------------------------------
extern "C" void kernel_launch(void* const* d_in, const int* in_sizes, int n_in,
                              void* d_out, int out_size, void* d_ws, size_t ws_size,
                              hipStream_t stream) {
  const float* x      = (const float*)d_in[0];
  const float* poi    = (const float*)d_in[1];
  const float* sat    = (const float*)d_in[2];
  const float* loc    = (const float*)d_in[3];
  const float* state  = (const float*)d_in[4];
  const float* poi_W  = (const float*)d_in[5];
  const float* poi_b  = (const float*)d_in[6];
  const float* poi_pe = (const float*)d_in[7];
  const float* sat_W  = (const float*)d_in[8];
  const float* sat_b  = (const float*)d_in[9];
  const float* sat_pe = (const float*)d_in[10];
  const float* xl_W   = (const float*)d_in[11];
  const float* xl_b   = (const float*)d_in[12];
  const float* x_pe   = (const float*)d_in[13];
  const float* loc_W  = (const float*)d_in[14];
  const float* loc_b  = (const float*)d_in[15];
  const float* loc_pe = (const float*)d_in[16];
  const float* q_W    = (const float*)d_in[17];
  const float* q_b    = (const float*)d_in[18];
  const float* v_W    = (const float*)d_in[19];
  const float* v_b    = (const float*)d_in[20];
  const float* imp_W  = (const float*)d_in[21];
  const float* imp_b  = (const float*)d_in[22];
  const float* unc_W1 = (const float*)d_in[23];
  const float* unc_b1 = (const float*)d_in[24];
  const float* unc_W2 = (const float*)d_in[25];
  const float* unc_b2 = (const float*)d_in[26];
  const float* out_W  = (const float*)d_in[27];

  float* out  = (float*)d_out;
  float* emb1 = out;                                   // [2048,4,128]
  float* xout = out + (size_t)2048 * 4 * 128;          // [8,2048,64,128]
  float* bm   = xout + (size_t)8 * 2048 * 64 * 128;    // [2048,4,1]

  float* T1  = (float*)d_ws;                            // 16384 f32
  float* cbt = T1 + 16384;                              // 128
  float* cb  = cbt + 128;                               // 128
  unsigned short* ctswz = (unsigned short*)(cb + 128);  // 16384 bf16
  unsigned short* pkw   = ctswz + 16384;                // PK_TOTAL bf16

  kW<<<dim3((PK_TOTAL + 255) / 256), dim3(256), 0, stream>>>(
      q_W, v_W, out_W, poi_W, sat_W, loc_W, xl_W, imp_W, unc_W1, pkw);
  kA1<<<dim3(129), dim3(128), 0, stream>>>(xl_W, v_W, xl_b, x_pe, v_b, T1, cbt);
  kA2<<<dim3(129), dim3(128), 0, stream>>>(T1, cbt, out_W, ctswz, cb);
  kB<<<dim3(256), dim3(256), 0, stream>>>(x, poi, sat, loc, state,
      poi_b, poi_pe, sat_b, sat_pe, loc_b, loc_pe, xl_b, x_pe,
      q_b, v_b, imp_b, unc_b1, unc_W2, unc_b2, pkw, emb1, bm);
  kC<<<dim3(2048), dim3(256), 0, stream>>>(x, ctswz, cb, xout);
}